// Round 3
// baseline (155.142 us; speedup 1.0000x reference)
//
#include <hip/hip_runtime.h>

#define HIDDEN   4096
#define RANK     256
#define G        16      // HIDDEN / RANK
#define TT       8       // tokens per block in expand kernel
#define NTHREADS 256

// ---------------------------------------------------------------------------
// k1: comp[t][r] = sum_gi x[t][gi*256 + r].  One wave per token.
// Coalesced float4 reads (1 KiB / wave inst), coalesced 1 KiB store.
// ---------------------------------------------------------------------------
__global__ __launch_bounds__(NTHREADS, 4)
void mora_compress(const float* __restrict__ x,     // [T, HIDDEN]
                   float* __restrict__ comp)        // [T, RANK]
{
    const int  lane = threadIdx.x & 63;
    const long t    = (long)blockIdx.x * 4 + (threadIdx.x >> 6);

    const float4* xrow = (const float4*)(x + t * HIDDEN);
    float4 a = xrow[lane];
    #pragma unroll
    for (int gi = 1; gi < G; ++gi) {
        const float4 v = xrow[gi * 64 + lane];
        a.x += v.x; a.y += v.y; a.z += v.z; a.w += v.w;
    }
    ((float4*)(comp + t * RANK))[lane] = a;
}

// ---------------------------------------------------------------------------
// k2: out[t][16k..16k+15] = sum_r comp[t][r] * M[r][k]
// Thread owns one column k = tid for TT tokens. comp is read with
// wave-UNIFORM addresses (scalarizes to s_load -> SGPR operand of v_fmac),
// keeping the LDS pipe free. M is read exactly once per block, coalesced.
// Stores staged through LDS for fully coalesced 1 KiB float4 writes.
// ---------------------------------------------------------------------------
__global__ __launch_bounds__(NTHREADS, 8)
void mora_expand(const float* __restrict__ comp,   // [T, RANK]
                 const float* __restrict__ M,      // [RANK, RANK]
                 float* __restrict__ out)          // [T, HIDDEN]
{
    __shared__ float outstage[TT][RANK];           // 8 KiB

    const int  tid  = threadIdx.x;
    const long tok0 = (long)blockIdx.x * TT;
    const int  k    = tid;

    float acc[TT];
    #pragma unroll
    for (int t = 0; t < TT; ++t) acc[t] = 0.f;

    #pragma unroll 2
    for (int r4 = 0; r4 < RANK / 4; ++r4) {
        const float* mcol = M + (size_t)r4 * 4 * RANK + k;
        const float m0 = mcol[0 * RANK];
        const float m1 = mcol[1 * RANK];
        const float m2 = mcol[2 * RANK];
        const float m3 = mcol[3 * RANK];
        #pragma unroll
        for (int t = 0; t < TT; ++t) {
            // uniform address (no tid) -> scalar load, SGPR broadcast
            const float4 c =
                *(const float4*)(comp + (tok0 + t) * RANK + r4 * 4);
            acc[t] += c.x * m0 + c.y * m1 + c.z * m2 + c.w * m3;
        }
    }

    #pragma unroll
    for (int t = 0; t < TT; ++t) outstage[t][k] = acc[t];
    __syncthreads();

    // coalesced expanded write: row is 1024 float4, wave writes contiguous 1 KiB
    #pragma unroll
    for (int t = 0; t < TT; ++t) {
        float4* orow = (float4*)(out + (tok0 + t) * HIDDEN);
        #pragma unroll
        for (int j = 0; j < 4; ++j) {
            const float v = outstage[t][(tid >> 2) + 64 * j];
            orow[tid + 256 * j] = make_float4(v, v, v, v);
        }
    }
}

// ---------------------------------------------------------------------------
// Fallback (R2 fused kernel) in case ws_size cannot hold comp.
// ---------------------------------------------------------------------------
__global__ __launch_bounds__(NTHREADS, 8)
void mora_fused(const float* __restrict__ x,
                const float* __restrict__ M,
                float* __restrict__ out)
{
    __shared__ float4 comp4[TT][RANK / 4];
    __shared__ float  outstage[TT][RANK];

    const int  tid  = threadIdx.x;
    const long tok0 = (long)blockIdx.x * TT;

    {
        const int rr = tid & 63;
        const int ts = tid >> 6;
        #pragma unroll
        for (int ti = 0; ti < TT / 4; ++ti) {
            const int t = ts * (TT / 4) + ti;
            const float4* xrow = (const float4*)(x + (tok0 + t) * HIDDEN);
            float4 a = xrow[rr];
            #pragma unroll
            for (int gi = 1; gi < G; ++gi) {
                float4 v = xrow[gi * 64 + rr];
                a.x += v.x; a.y += v.y; a.z += v.z; a.w += v.w;
            }
            comp4[t][rr] = a;
        }
    }
    __syncthreads();

    const int k = tid;
    float acc[TT];
    #pragma unroll
    for (int t = 0; t < TT; ++t) acc[t] = 0.f;

    #pragma unroll 2
    for (int r4 = 0; r4 < RANK / 4; ++r4) {
        const float* mcol = M + (size_t)r4 * 4 * RANK + k;
        const float m0 = mcol[0 * RANK];
        const float m1 = mcol[1 * RANK];
        const float m2 = mcol[2 * RANK];
        const float m3 = mcol[3 * RANK];
        #pragma unroll
        for (int t = 0; t < TT; ++t) {
            const float4 c = comp4[t][r4];
            acc[t] += c.x * m0 + c.y * m1 + c.z * m2 + c.w * m3;
        }
    }

    #pragma unroll
    for (int t = 0; t < TT; ++t) outstage[t][k] = acc[t];
    __syncthreads();

    #pragma unroll
    for (int t = 0; t < TT; ++t) {
        float4* orow = (float4*)(out + (tok0 + t) * HIDDEN);
        #pragma unroll
        for (int j = 0; j < 4; ++j) {
            const float v = outstage[t][(tid >> 2) + 64 * j];
            orow[tid + 256 * j] = make_float4(v, v, v, v);
        }
    }
}

extern "C" void kernel_launch(void* const* d_in, const int* in_sizes, int n_in,
                              void* d_out, int out_size, void* d_ws, size_t ws_size,
                              hipStream_t stream) {
    const float* x = (const float*)d_in[0];
    const float* M = (const float*)d_in[1];
    float* out     = (float*)d_out;

    const int T = in_sizes[0] / HIDDEN;  // 16384 tokens

    const size_t comp_bytes = (size_t)T * RANK * sizeof(float);
    if (ws_size >= comp_bytes) {
        float* comp = (float*)d_ws;
        hipLaunchKernelGGL(mora_compress, dim3(T / 4), dim3(NTHREADS), 0, stream,
                           x, comp);
        hipLaunchKernelGGL(mora_expand, dim3(T / TT), dim3(NTHREADS), 0, stream,
                           comp, M, out);
    } else {
        hipLaunchKernelGGL(mora_fused, dim3(T / TT), dim3(NTHREADS), 0, stream,
                           x, M, out);
    }
}

// Round 4
// 141.966 us; speedup vs baseline: 1.0928x; 1.0928x over previous
//
#include <hip/hip_runtime.h>

#define HIDDEN   4096
#define RANK     256
#define G        16      // HIDDEN / RANK
#define TW       4       // tokens per wave (= per block)
#define NTHREADS 64      // ONE wave per block: barriers are wave-local (free)

// One wave handles TW tokens end-to-end. Lane l owns output columns
// 4l..4l+3 for ALL 256 columns -> each comp broadcast is issued once per
// wave (not once per wave per column-slice), M rows are loaded coalesced
// (4 x b128 per r4 step) and reused across all TW tokens.
__global__ __launch_bounds__(NTHREADS, 4)
void mora_onewave(const float* __restrict__ x,   // [T, HIDDEN]
                  const float* __restrict__ M,   // [RANK, RANK] row-major
                  float* __restrict__ out)       // [T, HIDDEN]
{
    __shared__ float comp[TW][RANK];     // 4 KiB
    __shared__ float ostage[TW][RANK];   // 4 KiB

    const int  l    = threadIdx.x;       // lane 0..63
    const long tok0 = (long)blockIdx.x * TW;

    // ---- Phase 1: comp[t][r] = sum_gi x[t][gi*256 + r] ----
    // Lane l accumulates r = 4l..4l+3 (float4). Coalesced 1 KiB reads.
    #pragma unroll
    for (int t = 0; t < TW; ++t) {
        const float4* xrow = (const float4*)(x + (tok0 + t) * HIDDEN);
        float4 a = xrow[l];
        #pragma unroll
        for (int gi = 1; gi < G; ++gi) {
            const float4 v = xrow[l + 64 * gi];
            a.x += v.x; a.y += v.y; a.z += v.z; a.w += v.w;
        }
        ((float4*)comp[t])[l] = a;
    }
    __syncthreads();   // single-wave workgroup: near-free

    // ---- Phase 2: acc[t][c] = sum_r comp[t][r] * M[r][4l+c] ----
    float acc[TW][4];
    #pragma unroll
    for (int t = 0; t < TW; ++t)
        #pragma unroll
        for (int c = 0; c < 4; ++c) acc[t][c] = 0.f;

    const float* Mb = M + 4 * l;
    #pragma unroll 2
    for (int r4 = 0; r4 < RANK / 4; ++r4) {
        const float4 m0 = *(const float4*)(Mb + (size_t)(4 * r4 + 0) * RANK);
        const float4 m1 = *(const float4*)(Mb + (size_t)(4 * r4 + 1) * RANK);
        const float4 m2 = *(const float4*)(Mb + (size_t)(4 * r4 + 2) * RANK);
        const float4 m3 = *(const float4*)(Mb + (size_t)(4 * r4 + 3) * RANK);
        #pragma unroll
        for (int t = 0; t < TW; ++t) {
            const float4 c = ((const float4*)comp[t])[r4];  // LDS broadcast
            acc[t][0] += c.x * m0.x + c.y * m1.x + c.z * m2.x + c.w * m3.x;
            acc[t][1] += c.x * m0.y + c.y * m1.y + c.z * m2.y + c.w * m3.y;
            acc[t][2] += c.x * m0.z + c.y * m1.z + c.z * m2.z + c.w * m3.z;
            acc[t][3] += c.x * m0.w + c.y * m1.w + c.z * m2.w + c.w * m3.w;
        }
    }

    // ---- restage result rows for coalesced expanded writes ----
    #pragma unroll
    for (int t = 0; t < TW; ++t)
        ((float4*)ostage[t])[l] =
            make_float4(acc[t][0], acc[t][1], acc[t][2], acc[t][3]);
    __syncthreads();

    // ---- Phase 3: out[t][h] = ostage[t][h>>4], coalesced 1 KiB stores ----
    // float4 index p = l + 64s covers h = 4p..4p+3, all sharing col = p>>2.
    #pragma unroll
    for (int t = 0; t < TW; ++t) {
        float4* orow = (float4*)(out + (tok0 + t) * HIDDEN);
        #pragma unroll
        for (int s = 0; s < 16; ++s) {
            const float v = ostage[t][16 * s + (l >> 2)];  // 2-way bcast, conflict-free
            orow[l + 64 * s] = make_float4(v, v, v, v);
        }
    }
}

extern "C" void kernel_launch(void* const* d_in, const int* in_sizes, int n_in,
                              void* d_out, int out_size, void* d_ws, size_t ws_size,
                              hipStream_t stream) {
    const float* x = (const float*)d_in[0];
    const float* M = (const float*)d_in[1];
    float* out     = (float*)d_out;

    const int T = in_sizes[0] / HIDDEN;  // 16384 tokens

    hipLaunchKernelGGL(mora_onewave, dim3(T / TW), dim3(NTHREADS), 0, stream,
                       x, M, out);
}

// Round 5
// 125.239 us; speedup vs baseline: 1.2388x; 1.1336x over previous
//
#include <hip/hip_runtime.h>

#define HIDDEN 4096
#define RANK   256
#define G      16      // HIDDEN / RANK
#define NTH    1024    // 16 waves -> 1 block per CU (LDS-forced)
#define TPB    64      // tokens per block
#define TB     2       // tokens per inner batch
#define NB     2       // batches per wave (16 waves * TB * NB = 64 tokens)

__device__ __forceinline__ unsigned short bf16r(float v) {
    unsigned int u = __float_as_uint(v);
    return (unsigned short)((u + 0x7fffu + ((u >> 16) & 1u)) >> 16);  // RTNE
}
__device__ __forceinline__ float bf16f(unsigned short s) {
    return __uint_as_float(((unsigned int)s) << 16);
}

// Dynamic LDS layout:
//   [0, 131072)      : M as bf16, column-PERMUTED (k -> cp = (k&15)*16 + (k>>4))
//                      and row-XOR-swizzled (byte ^= (r&3)<<4), row stride 512 B
//   [131072, 147456) : comp bf16 [16 waves][TB][RANK]
__global__ __launch_bounds__(NTH, 4)
void mora_resident(const float* __restrict__ x,    // [T, HIDDEN]
                   const float* __restrict__ Mg,   // [RANK, RANK]
                   float* __restrict__ out)        // [T, HIDDEN]
{
    extern __shared__ unsigned char smem[];
    unsigned short* Ml   = (unsigned short*)smem;
    unsigned short* comp = (unsigned short*)(smem + 131072);

    const int tid = threadIdx.x;
    const int w   = tid >> 6;   // wave 0..15
    const int l   = tid & 63;   // lane
    const int q   = l >> 2;     // 0..15 : column phase (owns cols k = 16j + q)
    const int s   = l & 3;      // 0..3  : row split (owns rows r ≡ s mod 4)

    // ---- one-time stage: M f32 (global) -> bf16 permuted+swizzled (LDS) ----
    {
        const float4* M4 = (const float4*)Mg;
        #pragma unroll
        for (int i = 0; i < 16; ++i) {
            const int   idx = tid + (i << 10);   // 0..16383 float4s
            const float4 v  = M4[idx];
            const int r  = idx >> 6;
            const int k0 = (idx & 63) << 2;
            const float vv[4] = {v.x, v.y, v.z, v.w};
            #pragma unroll
            for (int e = 0; e < 4; ++e) {
                const int k  = k0 + e;
                const int cp = ((k & 15) << 4) | (k >> 4);
                unsigned int byte = ((unsigned)r << 9) + ((unsigned)cp << 1);
                byte ^= (unsigned)((r & 3) << 4);
                *(unsigned short*)(smem + byte) = bf16r(vv[e]);
            }
        }
    }
    __syncthreads();

    const long tokblk = (long)blockIdx.x * TPB + (long)w * (TB * NB);
    unsigned short* mycomp = comp + w * (TB * RANK);
    const unsigned sw = (unsigned)(s << 4);

    for (int b = 0; b < NB; ++b) {
        const long t0 = tokblk + (long)b * TB;

        // ---- phase 1: comp[t][r] = sum_gi x[t][gi*256+r]; lane owns r=4l..4l+3
        #pragma unroll
        for (int t = 0; t < TB; ++t) {
            const float4* xrow = (const float4*)(x + (t0 + t) * HIDDEN);
            float4 a = xrow[l];
            #pragma unroll
            for (int gi = 1; gi < G; ++gi) {
                const float4 vv = xrow[l + (gi << 6)];
                a.x += vv.x; a.y += vv.y; a.z += vv.z; a.w += vv.w;
            }
            ushort4 p;
            p.x = bf16r(a.x); p.y = bf16r(a.y); p.z = bf16r(a.z); p.w = bf16r(a.w);
            *(ushort4*)(mycomp + t * RANK + (l << 2)) = p;
        }
        // cross-lane (same wave) LDS visibility before phase 2 reads
        asm volatile("s_waitcnt lgkmcnt(0)" ::: "memory");

        // ---- phase 2: acc[t][j] = sum_r comp[t][r] * M[r][16j+q] ----
        float acc[TB][16];
        #pragma unroll
        for (int t = 0; t < TB; ++t)
            #pragma unroll
            for (int j = 0; j < 16; ++j) acc[t][j] = 0.f;

        #pragma unroll 2
        for (int r4 = 0; r4 < RANK / 4; ++r4) {
            const int r = (r4 << 2) | s;               // this lane's row
            const unsigned mb0 = ((unsigned)r << 9) + ((unsigned)q << 5);
            const uint4 A = *(const uint4*)(smem + (mb0 ^ sw));          // j=0..7
            const uint4 B = *(const uint4*)(smem + ((mb0 + 16u) ^ sw));  // j=8..15
            float m[16];
            m[ 0]=__uint_as_float(A.x<<16); m[ 1]=__uint_as_float(A.x&0xffff0000u);
            m[ 2]=__uint_as_float(A.y<<16); m[ 3]=__uint_as_float(A.y&0xffff0000u);
            m[ 4]=__uint_as_float(A.z<<16); m[ 5]=__uint_as_float(A.z&0xffff0000u);
            m[ 6]=__uint_as_float(A.w<<16); m[ 7]=__uint_as_float(A.w&0xffff0000u);
            m[ 8]=__uint_as_float(B.x<<16); m[ 9]=__uint_as_float(B.x&0xffff0000u);
            m[10]=__uint_as_float(B.y<<16); m[11]=__uint_as_float(B.y&0xffff0000u);
            m[12]=__uint_as_float(B.z<<16); m[13]=__uint_as_float(B.z&0xffff0000u);
            m[14]=__uint_as_float(B.w<<16); m[15]=__uint_as_float(B.w&0xffff0000u);
            #pragma unroll
            for (int t = 0; t < TB; ++t) {
                const float c = bf16f(mycomp[t * RANK + r]);  // 4-addr broadcast
                #pragma unroll
                for (int j = 0; j < 16; ++j) acc[t][j] += c * m[j];
            }
        }

        // ---- quad reduction: sum the 4 row-split partials (lanes 4q..4q+3)
        #pragma unroll
        for (int t = 0; t < TB; ++t)
            #pragma unroll
            for (int j = 0; j < 16; ++j) {
                float v = acc[t][j];
                v += __shfl_xor(v, 1);
                v += __shfl_xor(v, 2);
                acc[t][j] = v;
            }

        // ---- phase 3: fully coalesced stores, zero restage ----
        // store instr j: lane l writes float4 #(64j+l) -> h=256j+4l, whose
        // col is 16j+q = exactly this lane's acc[t][j]; quad lanes fill the
        // 4 float4s of that column's 64 B expansion.
        #pragma unroll
        for (int t = 0; t < TB; ++t) {
            float4* orow = (float4*)(out + (t0 + t) * HIDDEN);
            #pragma unroll
            for (int j = 0; j < 16; ++j) {
                const float vv = acc[t][j];
                orow[(j << 6) + l] = make_float4(vv, vv, vv, vv);
            }
        }
    }
}

extern "C" void kernel_launch(void* const* d_in, const int* in_sizes, int n_in,
                              void* d_out, int out_size, void* d_ws, size_t ws_size,
                              hipStream_t stream) {
    const float* x = (const float*)d_in[0];
    const float* M = (const float*)d_in[1];
    float* out     = (float*)d_out;

    const int T = in_sizes[0] / HIDDEN;   // 16384 tokens
    const int smem_bytes = 147456;        // 144 KiB dynamic LDS

    (void)hipFuncSetAttribute((const void*)mora_resident,
                              hipFuncAttributeMaxDynamicSharedMemorySize,
                              smem_bytes);

    hipLaunchKernelGGL(mora_resident, dim3(T / TPB), dim3(NTH), smem_bytes,
                       stream, x, M, out);
}